// Round 12
// baseline (103.096 us; speedup 1.0000x reference)
//
#include <hip/hip_runtime.h>

#define N_TOT 8192
#define NS 4096
#define D 256                 // elements per row; fp8 => also bytes per row
#define NB 64                 // 8192/128 tiles per dim
#define NTRI (NB*(NB+1)/2)    // 2080 upper-triangle tiles
#define HALF_B 32

typedef float f32x16 __attribute__((ext_vector_type(16)));
typedef float f32x2 __attribute__((ext_vector_type(2)));
typedef int i32x4 __attribute__((ext_vector_type(4)));
typedef int i32x8 __attribute__((ext_vector_type(8)));

__device__ __forceinline__ void gload16(const void* g, void* l) {
  __builtin_amdgcn_global_load_lds(
      (const __attribute__((address_space(1))) unsigned int*)g,
      (__attribute__((address_space(3))) unsigned int*)l,
      16, 0, 0);
}

// ---- K1: one pass: fp8 e4m3 convert + row sq-norms + per-block partials ----
// 512 blocks x 256 threads, 16 rows/block (2 blocks/CU for latency hiding)
__global__ void k_prep(const float* __restrict__ src, const float* __restrict__ tgt,
                       unsigned char* __restrict__ Xb, float* __restrict__ sqv,
                       float* __restrict__ pm, float* __restrict__ wsqp) {
  __shared__ float colacc[256];
  __shared__ float wred[4];
  int t = threadIdx.x, l = t & 63, w = t >> 6;
  colacc[t] = 0.f;
  __syncthreads();
  int base = blockIdx.x * 16;
  float c0 = 0.f, c1 = 0.f, c2 = 0.f, c3 = 0.f;
  float wsq = 0.f;
  #pragma unroll
  for (int r = 0; r < 4; ++r) {
    int row = base + w * 4 + r;
    const float* p = (row < NS) ? (src + (size_t)row * D) : (tgt + (size_t)(row - NS) * D);
    float4 v = ((const float4*)p)[l];
    int pk = __builtin_amdgcn_cvt_pk_fp8_f32(v.x, v.y, 0, false);   // bytes 0,1
    pk = __builtin_amdgcn_cvt_pk_fp8_f32(v.z, v.w, pk, true);       // bytes 2,3
    ((int*)(Xb + (size_t)row * D))[l] = pk;                         // 4 B/lane coalesced
    c0 += v.x; c1 += v.y; c2 += v.z; c3 += v.w;
    float s = fmaf(v.x, v.x, fmaf(v.y, v.y, fmaf(v.z, v.z, v.w * v.w)));
    for (int o = 32; o > 0; o >>= 1) s += __shfl_down(s, o, 64);
    if (l == 0) { sqv[row] = s; wsq += s; }
  }
  atomicAdd(&colacc[4 * l + 0], c0);
  atomicAdd(&colacc[4 * l + 1], c1);
  atomicAdd(&colacc[4 * l + 2], c2);
  atomicAdd(&colacc[4 * l + 3], c3);
  if (l == 0) wred[w] = wsq;
  __syncthreads();
  pm[blockIdx.x * 256 + t] = colacc[t];
  if (t == 0) wsqp[blockIdx.x] = (wred[0] + wred[1]) + (wred[2] + wred[3]);
}

// ---- K2: reduce partials, finalize bandwidth in fp64 (1 block) ----
__global__ void k_bw(const float* __restrict__ pm, const float* __restrict__ wsqp,
                     float* __restrict__ coef) {
  __shared__ double red[256];
  int t = threadIdx.x;
  float cs = 0.f;
  for (int b = 0; b < 512; ++b) cs += pm[b * 256 + t];
  red[t] = (double)cs * (double)cs;
  __syncthreads();
  for (int s = 128; s > 0; s >>= 1) {
    if (t < s) red[t] += red[t + s];
    __syncthreads();
  }
  double msq = red[0];
  __syncthreads();
  double ws = (double)wsqp[t] + (double)wsqp[t + 256];
  red[t] = ws;
  __syncthreads();
  for (int s = 128; s > 0; s >>= 1) {
    if (t < s) red[t] += red[t + s];
    __syncthreads();
  }
  if (t == 0) {
    double Sv = red[0];
    double n = (double)N_TOT;
    double sumL2 = 2.0 * n * Sv - 2.0 * msq;
    double bw = sumL2 / (n * n - n) / 4.0;        // / KERNEL_MUL**(KERNEL_NUM//2)
    double c4 = 1.0 / (bw * 16.0 + 1e-6);         // widest kernel (k=4)
    coef[0] = (float)(c4 * 1.4426950408889634);   // * log2(e) for exp2
  }
}

// ---- K3: 128x128 upper-tri tiles, MX-scaled fp8, BK=128 two-stage K-loop ----
// 3 K-loop barriers (was 7): each stage = whole 128B half-row per matrix,
// 16 KB/matrix LDS, 32 KB/block total -> ~4 blocks/CU. Same total traffic,
// same MFMA/ds_read counts as BK=64; only latency-exposure count drops.
__global__ __launch_bounds__(256) void k_main(
    const unsigned char* __restrict__ Xb, const float* __restrict__ sqv,
    const float* __restrict__ coef, float* __restrict__ bpart) {
  // triangular decode: block b -> (bi, bj), bi <= bj
  int b = blockIdx.x;
  int bi = (int)((2.f * NB + 1.f - sqrtf((float)((2 * NB + 1) * (2 * NB + 1) - 8 * b))) * 0.5f);
  if (bi < 0) bi = 0;
  if (bi > NB - 1) bi = NB - 1;
  while ((bi + 1) * (2 * NB - bi) / 2 <= b) ++bi;
  while (bi * (2 * NB - bi + 1) / 2 > b) --bi;
  int bj = bi + (b - bi * (2 * NB - bi + 1) / 2);

  __shared__ unsigned char ldsA[128 * 128];  // 16 KB [row][128B stage-slice]
  __shared__ unsigned char ldsB[128 * 128];  // 16 KB
  __shared__ float sqA[128], sqB[128];
  __shared__ float redw[4];

  int t = threadIdx.x, l = t & 63, w = t >> 6;
  int lr = l & 31, half = l >> 5;
  int waveRow = w >> 1, waveCol = w & 1;

  if (t < 128) sqA[t] = sqv[bi * 128 + t];
  else         sqB[t - 128] = sqv[bj * 128 + (t - 128)];
  float A4 = coef[0];

  const unsigned char* arow = Xb + (size_t)bi * 128 * D;
  const unsigned char* brow = Xb + (size_t)bj * 128 * D;

  f32x16 acc[2][2] = {};

  for (int ko = 0; ko < 2; ++ko) {
    if (ko) __syncthreads();
    int kOff = ko * 128;                    // byte offset in row
    #pragma unroll
    for (int p = 0; p < 4; ++p) {           // 1024 16B segs per matrix
      int seg = p * 256 + t;
      int row = seg >> 3;
      int kb = (seg & 7) ^ (row & 7);       // xor swizzle on the global source side
      int goff = row * D + kOff + kb * 16;
      gload16(arow + goff, &ldsA[(p * 256 + t) * 16]);
      gload16(brow + goff, &ldsB[(p * 256 + t) * 16]);
    }
    __syncthreads();
    #pragma unroll
    for (int win = 0; win < 2; ++win) {     // two K=64 windows per stage
      int c0 = win * 4 + 2 * half;          // lane's logical 16B chunks
      int c1 = c0 + 1;
      i32x8 aF[2];
      #pragma unroll
      for (int rb = 0; rb < 2; ++rb) {
        int rowA = waveRow * 64 + rb * 32 + lr;
        int sw = rowA & 7;
        i32x4 lo = *(const i32x4*)&ldsA[rowA * 128 + (c0 ^ sw) * 16];
        i32x4 hi = *(const i32x4*)&ldsA[rowA * 128 + (c1 ^ sw) * 16];
        aF[rb] = (i32x8){lo.x, lo.y, lo.z, lo.w, hi.x, hi.y, hi.z, hi.w};
      }
      #pragma unroll
      for (int cb = 0; cb < 2; ++cb) {
        int rowB = waveCol * 64 + cb * 32 + lr;
        int sw = rowB & 7;
        i32x4 lo = *(const i32x4*)&ldsB[rowB * 128 + (c0 ^ sw) * 16];
        i32x4 hi = *(const i32x4*)&ldsB[rowB * 128 + (c1 ^ sw) * 16];
        i32x8 bF = (i32x8){lo.x, lo.y, lo.z, lo.w, hi.x, hi.y, hi.z, hi.w};
        #pragma unroll
        for (int rb = 0; rb < 2; ++rb)
          acc[rb][cb] = __builtin_amdgcn_mfma_scale_f32_32x32x64_f8f6f4(
              aF[rb], bF, acc[rb][cb], 0, 0, 0, 127, 0, 127);
      }
    }
  }

  // Packed epilogue: tt = 2A4*dot - A4*sqi - A4*sqj ; e = exp2(tt)
  // sum5 = e+e^2+e^4+e^8+e^16 (exp-squaring; bw_k = bw*2^k exactly)
  // C/D layout (shape-determined, dtype-independent): col=lane&31,
  // row=(r&3)+8*(r>>2)+4*(lane>>5)
  float c2A4 = 2.f * A4, nA4 = -A4;
  f32x2 lsum2 = {0.f, 0.f};
  bool diag = (bi == bj);
  #pragma unroll
  for (int cb = 0; cb < 2; ++cb) {
    int jj = waveCol * 64 + cb * 32 + lr;
    float bjv = nA4 * sqB[jj];
    #pragma unroll
    for (int rb = 0; rb < 2; ++rb) {
      #pragma unroll
      for (int r = 0; r < 16; r += 2) {
        int ii = waveRow * 64 + rb * 32 + (r & 3) + 8 * (r >> 2) + 4 * half;
        f32x2 dot2 = {acc[rb][cb][r], acc[rb][cb][r + 1]};
        f32x2 sq2 = {sqA[ii], sqA[ii + 1]};
        f32x2 tt = c2A4 * dot2 + (nA4 * sq2 + bjv);
        f32x2 e;
        e.x = __builtin_amdgcn_exp2f(tt.x);
        e.y = __builtin_amdgcn_exp2f(tt.y);
        f32x2 e2 = e * e, e4 = e2 * e2, e8 = e4 * e4, e16 = e8 * e8;
        f32x2 kern = ((e + e2) + (e4 + e8)) + e16;
        if (diag) {                          // block-uniform branch
          if (ii == jj) kern.x = 0.f;
          if (ii + 1 == jj) kern.y = 0.f;
        }
        lsum2 += kern;
      }
    }
  }
  float lsum = lsum2.x + lsum2.y;
  for (int o = 32; o > 0; o >>= 1) lsum += __shfl_down(lsum, o, 64);
  if (l == 0) redw[w] = lsum;
  __syncthreads();
  if (t == 0) {
    float tot = (redw[0] + redw[1]) + (redw[2] + redw[3]);
    float wgt = diag ? 1.f : 2.f;                               // symmetry weight
    float sgn = ((bi < HALF_B) == (bj < HALF_B)) ? 1.f : -1.f;  // s_i * s_j
    bpart[b] = tot * wgt * sgn;
  }
}

// ---- K4: final fp64 reduction + analytic diagonal + mean ----
__global__ void k_final(const float* __restrict__ bpart, float* __restrict__ out) {
  __shared__ double red[256];
  int t = threadIdx.x;
  double s = 0.0;
  for (int k = 0; k < 9; ++k) {
    int idx = k * 256 + t;
    if (idx < NTRI) s += (double)bpart[idx];
  }
  red[t] = s;
  __syncthreads();
  for (int st = 128; st > 0; st >>= 1) {
    if (t < st) red[t] += red[t + st];
    __syncthreads();
  }
  if (t == 0) {
    double total = red[0] + 5.0 * (double)N_TOT;  // diagonal: K_ii = 5, sign +1
    out[0] = (float)(total / ((double)NS * (double)NS));
  }
}

extern "C" void kernel_launch(void* const* d_in, const int* in_sizes, int n_in,
                              void* d_out, int out_size, void* d_ws, size_t ws_size,
                              hipStream_t stream) {
  const float* src = (const float*)d_in[0];
  const float* tgt = (const float*)d_in[1];
  float* out = (float*)d_out;
  char* ws = (char*)d_ws;
  unsigned char* Xb = (unsigned char*)ws;                       // 2 MB fp8 row-major
  float* sqv  = (float*)(ws + (4u << 20));                      // 32 KB row sq-norms
  float* pm   = (float*)(ws + (4u << 20) + (32u << 10));        // 512 KB col partials
  float* wsqp = (float*)(ws + (4u << 20) + (544u << 10));       // 2 KB sq partials
  float* coef = (float*)(ws + (4u << 20) + (546u << 10));       // 4 B
  float* bpart = (float*)(ws + (4u << 20) + (547u << 10));      // 8.3 KB tile partials

  hipLaunchKernelGGL(k_prep, dim3(512), dim3(256), 0, stream, src, tgt, Xb, sqv, pm, wsqp);
  hipLaunchKernelGGL(k_bw, dim3(1), dim3(256), 0, stream, pm, wsqp, coef);
  hipLaunchKernelGGL(k_main, dim3(NTRI), dim3(256), 0, stream, Xb, sqv, coef, bpart);
  hipLaunchKernelGGL(k_final, dim3(1), dim3(256), 0, stream, bpart, out);
}

// Round 13
// 102.191 us; speedup vs baseline: 1.0089x; 1.0089x over previous
//
#include <hip/hip_runtime.h>

#define N_TOT 8192
#define NS 4096
#define D 256                 // elements per row; fp8 => also bytes per row
#define NB 64                 // 8192/128 tiles per dim
#define NTRI (NB*(NB+1)/2)    // 2080 upper-triangle tiles
#define HALF_B 32

typedef float f32x16 __attribute__((ext_vector_type(16)));
typedef float f32x2 __attribute__((ext_vector_type(2)));
typedef int i32x4 __attribute__((ext_vector_type(4)));
typedef int i32x8 __attribute__((ext_vector_type(8)));

__device__ __forceinline__ void gload16(const void* g, void* l) {
  __builtin_amdgcn_global_load_lds(
      (const __attribute__((address_space(1))) unsigned int*)g,
      (__attribute__((address_space(3))) unsigned int*)l,
      16, 0, 0);
}

// ---- K1: one pass: fp8 e4m3 convert + row sq-norms + colsum/S atomics ----
// 256 blocks x 256 threads (r11 geometry); global atomics (r5-proven),
// colsum/S zeroed by captured hipMemsetAsync.
__global__ void k_prep(const float* __restrict__ src, const float* __restrict__ tgt,
                       unsigned char* __restrict__ Xb, float* __restrict__ sqv,
                       float* __restrict__ colsum, float* __restrict__ S) {
  __shared__ float colacc[256];
  __shared__ float wred[4];
  int t = threadIdx.x, l = t & 63, w = t >> 6;
  colacc[t] = 0.f;
  __syncthreads();
  int base = blockIdx.x * 32;
  float c0 = 0.f, c1 = 0.f, c2 = 0.f, c3 = 0.f;
  float wsq = 0.f;
  #pragma unroll
  for (int r = 0; r < 8; ++r) {
    int row = base + w * 8 + r;
    const float* p = (row < NS) ? (src + (size_t)row * D) : (tgt + (size_t)(row - NS) * D);
    float4 v = ((const float4*)p)[l];
    int pk = __builtin_amdgcn_cvt_pk_fp8_f32(v.x, v.y, 0, false);   // bytes 0,1
    pk = __builtin_amdgcn_cvt_pk_fp8_f32(v.z, v.w, pk, true);       // bytes 2,3
    ((int*)(Xb + (size_t)row * D))[l] = pk;                         // 4 B/lane coalesced
    c0 += v.x; c1 += v.y; c2 += v.z; c3 += v.w;
    float s = fmaf(v.x, v.x, fmaf(v.y, v.y, fmaf(v.z, v.z, v.w * v.w)));
    for (int o = 32; o > 0; o >>= 1) s += __shfl_down(s, o, 64);
    if (l == 0) { sqv[row] = s; wsq += s; }
  }
  atomicAdd(&colacc[4 * l + 0], c0);
  atomicAdd(&colacc[4 * l + 1], c1);
  atomicAdd(&colacc[4 * l + 2], c2);
  atomicAdd(&colacc[4 * l + 3], c3);
  if (l == 0) wred[w] = wsq;
  __syncthreads();
  atomicAdd(&colsum[t], colacc[t]);
  if (t == 0) atomicAdd(S, (wred[0] + wred[1]) + (wred[2] + wred[3]));
}

// ---- K2: finalize bandwidth in fp64 (reads 257 floats; 1 block) ----
__global__ void k_bw(const float* __restrict__ colsum, const float* __restrict__ S,
                     float* __restrict__ coef) {
  __shared__ double red[256];
  int t = threadIdx.x;
  double c = (double)colsum[t];
  red[t] = c * c;
  __syncthreads();
  for (int s = 128; s > 0; s >>= 1) {
    if (t < s) red[t] += red[t + s];
    __syncthreads();
  }
  if (t == 0) {
    double msq = red[0];
    double Sv = (double)S[0];
    double n = (double)N_TOT;
    double sumL2 = 2.0 * n * Sv - 2.0 * msq;
    double bw = sumL2 / (n * n - n) / 4.0;        // / KERNEL_MUL**(KERNEL_NUM//2)
    double c4 = 1.0 / (bw * 16.0 + 1e-6);         // widest kernel (k=4)
    coef[0] = (float)(c4 * 1.4426950408889634);   // * log2(e) for exp2
  }
}

// ---- K3: 128x128 upper-tri tiles, MX-scaled fp8 32x32x64 (r11 exact) ----
// BK=64, 8 KB + 8 KB LDS -> 8 blocks/CU (wave-slot limit) — the measured
// optimum. r12 lesson: bigger stages halve residency and regress; cross-block
// TLP is what hides the barrier drains here.
__global__ __launch_bounds__(256) void k_main(
    const unsigned char* __restrict__ Xb, const float* __restrict__ sqv,
    const float* __restrict__ coef, float* __restrict__ bpart) {
  // triangular decode: block b -> (bi, bj), bi <= bj
  int b = blockIdx.x;
  int bi = (int)((2.f * NB + 1.f - sqrtf((float)((2 * NB + 1) * (2 * NB + 1) - 8 * b))) * 0.5f);
  if (bi < 0) bi = 0;
  if (bi > NB - 1) bi = NB - 1;
  while ((bi + 1) * (2 * NB - bi) / 2 <= b) ++bi;
  while (bi * (2 * NB - bi + 1) / 2 > b) --bi;
  int bj = bi + (b - bi * (2 * NB - bi + 1) / 2);

  __shared__ unsigned char ldsA[128 * 64];   // 8 KB  [row][64B stage-slice]
  __shared__ unsigned char ldsB[128 * 64];   // 8 KB
  __shared__ float sqA[128], sqB[128];
  __shared__ float redw[4];

  int t = threadIdx.x, l = t & 63, w = t >> 6;
  int lr = l & 31, half = l >> 5;
  int waveRow = w >> 1, waveCol = w & 1;

  if (t < 128) sqA[t] = sqv[bi * 128 + t];
  else         sqB[t - 128] = sqv[bj * 128 + (t - 128)];
  float A4 = coef[0];

  const unsigned char* arow = Xb + (size_t)bi * 128 * D;
  const unsigned char* brow = Xb + (size_t)bj * 128 * D;

  f32x16 acc[2][2] = {};
  int cLo = 2 * half, cHi = 2 * half + 1;   // lane's logical 16B chunks

  for (int ko = 0; ko < 4; ++ko) {
    if (ko) __syncthreads();
    int kOff = ko * 64;                     // byte offset in row
    #pragma unroll
    for (int p = 0; p < 2; ++p) {           // 512 16B segs per matrix
      int seg = p * 256 + t;
      int row = seg >> 2;
      int kb = (seg & 3) ^ (row & 3) ^ ((row >> 2) & 3);
      int goff = row * D + kOff + kb * 16;
      gload16(arow + goff, &ldsA[(p * 256 + w * 64) * 16]);
      gload16(brow + goff, &ldsB[(p * 256 + w * 64) * 16]);
    }
    __syncthreads();
    i32x8 aF[2];
    #pragma unroll
    for (int rb = 0; rb < 2; ++rb) {
      int rowA = waveRow * 64 + rb * 32 + lr;
      int sw = (rowA & 3) ^ ((rowA >> 2) & 3);
      i32x4 lo = *(const i32x4*)&ldsA[rowA * 64 + (cLo ^ sw) * 16];
      i32x4 hi = *(const i32x4*)&ldsA[rowA * 64 + (cHi ^ sw) * 16];
      aF[rb] = (i32x8){lo.x, lo.y, lo.z, lo.w, hi.x, hi.y, hi.z, hi.w};
    }
    #pragma unroll
    for (int cb = 0; cb < 2; ++cb) {
      int rowB = waveCol * 64 + cb * 32 + lr;
      int sw = (rowB & 3) ^ ((rowB >> 2) & 3);
      i32x4 lo = *(const i32x4*)&ldsB[rowB * 64 + (cLo ^ sw) * 16];
      i32x4 hi = *(const i32x4*)&ldsB[rowB * 64 + (cHi ^ sw) * 16];
      i32x8 bF = (i32x8){lo.x, lo.y, lo.z, lo.w, hi.x, hi.y, hi.z, hi.w};
      #pragma unroll
      for (int rb = 0; rb < 2; ++rb)
        acc[rb][cb] = __builtin_amdgcn_mfma_scale_f32_32x32x64_f8f6f4(
            aF[rb], bF, acc[rb][cb], 0, 0, 0, 127, 0, 127);
    }
  }

  // Packed epilogue: tt = 2A4*dot - A4*sqi - A4*sqj ; e = exp2(tt)
  // sum5 = e+e^2+e^4+e^8+e^16 (exp-squaring; bw_k = bw*2^k exactly)
  // C/D layout (shape-determined, dtype-independent): col=lane&31,
  // row=(r&3)+8*(r>>2)+4*(lane>>5)
  float c2A4 = 2.f * A4, nA4 = -A4;
  f32x2 lsum2 = {0.f, 0.f};
  bool diag = (bi == bj);
  #pragma unroll
  for (int cb = 0; cb < 2; ++cb) {
    int jj = waveCol * 64 + cb * 32 + lr;
    float bjv = nA4 * sqB[jj];
    #pragma unroll
    for (int rb = 0; rb < 2; ++rb) {
      #pragma unroll
      for (int r = 0; r < 16; r += 2) {
        int ii = waveRow * 64 + rb * 32 + (r & 3) + 8 * (r >> 2) + 4 * half;
        f32x2 dot2 = {acc[rb][cb][r], acc[rb][cb][r + 1]};
        f32x2 sq2 = {sqA[ii], sqA[ii + 1]};
        f32x2 tt = c2A4 * dot2 + (nA4 * sq2 + bjv);
        f32x2 e;
        e.x = __builtin_amdgcn_exp2f(tt.x);
        e.y = __builtin_amdgcn_exp2f(tt.y);
        f32x2 e2 = e * e, e4 = e2 * e2, e8 = e4 * e4, e16 = e8 * e8;
        f32x2 kern = ((e + e2) + (e4 + e8)) + e16;
        if (diag) {                          // block-uniform branch
          if (ii == jj) kern.x = 0.f;
          if (ii + 1 == jj) kern.y = 0.f;
        }
        lsum2 += kern;
      }
    }
  }
  float lsum = lsum2.x + lsum2.y;
  for (int o = 32; o > 0; o >>= 1) lsum += __shfl_down(lsum, o, 64);
  if (l == 0) redw[w] = lsum;
  __syncthreads();
  if (t == 0) {
    float tot = (redw[0] + redw[1]) + (redw[2] + redw[3]);
    float wgt = diag ? 1.f : 2.f;                               // symmetry weight
    float sgn = ((bi < HALF_B) == (bj < HALF_B)) ? 1.f : -1.f;  // s_i * s_j
    bpart[b] = tot * wgt * sgn;
  }
}

// ---- K4: final fp64 reduction + analytic diagonal + mean ----
__global__ void k_final(const float* __restrict__ bpart, float* __restrict__ out) {
  __shared__ double red[256];
  int t = threadIdx.x;
  double s = 0.0;
  for (int k = 0; k < 9; ++k) {
    int idx = k * 256 + t;
    if (idx < NTRI) s += (double)bpart[idx];
  }
  red[t] = s;
  __syncthreads();
  for (int st = 128; st > 0; st >>= 1) {
    if (t < st) red[t] += red[t + st];
    __syncthreads();
  }
  if (t == 0) {
    double total = red[0] + 5.0 * (double)N_TOT;  // diagonal: K_ii = 5, sign +1
    out[0] = (float)(total / ((double)NS * (double)NS));
  }
}

extern "C" void kernel_launch(void* const* d_in, const int* in_sizes, int n_in,
                              void* d_out, int out_size, void* d_ws, size_t ws_size,
                              hipStream_t stream) {
  const float* src = (const float*)d_in[0];
  const float* tgt = (const float*)d_in[1];
  float* out = (float*)d_out;
  char* ws = (char*)d_ws;
  unsigned char* Xb = (unsigned char*)ws;                       // 2 MB fp8 row-major
  float* sqv   = (float*)(ws + (4u << 20));                     // 32 KB row sq-norms
  float* colsum = (float*)(ws + (4u << 20) + (32u << 10));      // 1 KB column sums
  float* S     = (float*)(ws + (4u << 20) + (32u << 10) + 1024);// 4 B (adjacent)
  float* coef  = (float*)(ws + (4u << 20) + (34u << 10));       // 4 B
  float* bpart = (float*)(ws + (4u << 20) + (35u << 10));       // 8.3 KB tile partials

  hipMemsetAsync(colsum, 0, 1028, stream);                      // colsum[256] + S
  hipLaunchKernelGGL(k_prep, dim3(256), dim3(256), 0, stream, src, tgt, Xb, sqv, colsum, S);
  hipLaunchKernelGGL(k_bw, dim3(1), dim3(256), 0, stream, colsum, S, coef);
  hipLaunchKernelGGL(k_main, dim3(NTRI), dim3(256), 0, stream, Xb, sqv, coef, bpart);
  hipLaunchKernelGGL(k_final, dim3(1), dim3(256), 0, stream, bpart, out);
}

// Round 14
// 97.565 us; speedup vs baseline: 1.0567x; 1.0474x over previous
//
#include <hip/hip_runtime.h>

#define N_TOT 8192
#define NS 4096
#define D 256                 // elements per row; fp8 => also bytes per row
#define NB 64                 // 8192/128 tiles per dim
#define NTRI (NB*(NB+1)/2)    // 2080 upper-triangle tiles
#define HALF_B 32

typedef float f32x16 __attribute__((ext_vector_type(16)));
typedef float f32x2 __attribute__((ext_vector_type(2)));
typedef int i32x4 __attribute__((ext_vector_type(4)));
typedef int i32x8 __attribute__((ext_vector_type(8)));

__device__ __forceinline__ void gload16(const void* g, void* l) {
  __builtin_amdgcn_global_load_lds(
      (const __attribute__((address_space(1))) unsigned int*)g,
      (__attribute__((address_space(3))) unsigned int*)l,
      16, 0, 0);
}

// ---- K1: one pass: fp8 e4m3 convert + row sq-norms + per-block partials ----
// (r11 exact: atomic-free, no zeroing pass; 256 blocks x 256 threads)
__global__ void k_prep(const float* __restrict__ src, const float* __restrict__ tgt,
                       unsigned char* __restrict__ Xb, float* __restrict__ sqv,
                       float* __restrict__ pm, float* __restrict__ wsqp) {
  __shared__ float colacc[256];
  __shared__ float wred[4];
  int t = threadIdx.x, l = t & 63, w = t >> 6;
  colacc[t] = 0.f;
  __syncthreads();
  int base = blockIdx.x * 32;
  float c0 = 0.f, c1 = 0.f, c2 = 0.f, c3 = 0.f;
  float wsq = 0.f;
  #pragma unroll
  for (int r = 0; r < 8; ++r) {
    int row = base + w * 8 + r;
    const float* p = (row < NS) ? (src + (size_t)row * D) : (tgt + (size_t)(row - NS) * D);
    float4 v = ((const float4*)p)[l];
    int pk = __builtin_amdgcn_cvt_pk_fp8_f32(v.x, v.y, 0, false);   // bytes 0,1
    pk = __builtin_amdgcn_cvt_pk_fp8_f32(v.z, v.w, pk, true);       // bytes 2,3
    ((int*)(Xb + (size_t)row * D))[l] = pk;                         // 4 B/lane coalesced
    c0 += v.x; c1 += v.y; c2 += v.z; c3 += v.w;
    float s = fmaf(v.x, v.x, fmaf(v.y, v.y, fmaf(v.z, v.z, v.w * v.w)));
    for (int o = 32; o > 0; o >>= 1) s += __shfl_down(s, o, 64);
    if (l == 0) { sqv[row] = s; wsq += s; }
  }
  atomicAdd(&colacc[4 * l + 0], c0);
  atomicAdd(&colacc[4 * l + 1], c1);
  atomicAdd(&colacc[4 * l + 2], c2);
  atomicAdd(&colacc[4 * l + 3], c3);
  if (l == 0) wred[w] = wsq;
  __syncthreads();
  pm[blockIdx.x * 256 + t] = colacc[t];
  if (t == 0) wsqp[blockIdx.x] = (wred[0] + wred[1]) + (wred[2] + wred[3]);
}

// ---- K2: reduce partials, finalize bandwidth in fp64 (1 block) ----
__global__ void k_bw(const float* __restrict__ pm, const float* __restrict__ wsqp,
                     float* __restrict__ coef) {
  __shared__ double red[256];
  int t = threadIdx.x;
  float cs = 0.f;
  for (int b = 0; b < 256; ++b) cs += pm[b * 256 + t];
  red[t] = (double)cs * (double)cs;
  __syncthreads();
  for (int s = 128; s > 0; s >>= 1) {
    if (t < s) red[t] += red[t + s];
    __syncthreads();
  }
  double msq = red[0];
  __syncthreads();
  red[t] = (double)wsqp[t];
  __syncthreads();
  for (int s = 128; s > 0; s >>= 1) {
    if (t < s) red[t] += red[t + s];
    __syncthreads();
  }
  if (t == 0) {
    double Sv = red[0];
    double n = (double)N_TOT;
    double sumL2 = 2.0 * n * Sv - 2.0 * msq;
    double bw = sumL2 / (n * n - n) / 4.0;        // / KERNEL_MUL**(KERNEL_NUM//2)
    double c4 = 1.0 / (bw * 16.0 + 1e-6);         // widest kernel (k=4)
    coef[0] = (float)(c4 * 1.4426950408889634);   // * log2(e) for exp2
  }
}

// ---- K3: 128x128 upper-tri tiles, MX-scaled fp8 32x32x64 MFMA (unit scales) ----
// r11 exact — the measured optimum: BK=64, 8+8 KB LDS, 8 blocks/CU.
__global__ __launch_bounds__(256) void k_main(
    const unsigned char* __restrict__ Xb, const float* __restrict__ sqv,
    const float* __restrict__ coef, float* __restrict__ bpart) {
  // triangular decode: block b -> (bi, bj), bi <= bj
  int b = blockIdx.x;
  int bi = (int)((2.f * NB + 1.f - sqrtf((float)((2 * NB + 1) * (2 * NB + 1) - 8 * b))) * 0.5f);
  if (bi < 0) bi = 0;
  if (bi > NB - 1) bi = NB - 1;
  while ((bi + 1) * (2 * NB - bi) / 2 <= b) ++bi;
  while (bi * (2 * NB - bi + 1) / 2 > b) --bi;
  int bj = bi + (b - bi * (2 * NB - bi + 1) / 2);

  __shared__ unsigned char ldsA[128 * 64];   // 8 KB  [row][64B stage-slice]
  __shared__ unsigned char ldsB[128 * 64];   // 8 KB
  __shared__ float sqA[128], sqB[128];
  __shared__ float redw[4];

  int t = threadIdx.x, l = t & 63, w = t >> 6;
  int lr = l & 31, half = l >> 5;
  int waveRow = w >> 1, waveCol = w & 1;

  if (t < 128) sqA[t] = sqv[bi * 128 + t];
  else         sqB[t - 128] = sqv[bj * 128 + (t - 128)];
  float A4 = coef[0];

  const unsigned char* arow = Xb + (size_t)bi * 128 * D;
  const unsigned char* brow = Xb + (size_t)bj * 128 * D;

  f32x16 acc[2][2] = {};
  int cLo = 2 * half, cHi = 2 * half + 1;   // lane's logical 16B chunks

  for (int ko = 0; ko < 4; ++ko) {
    if (ko) __syncthreads();
    int kOff = ko * 64;                     // byte offset in row
    #pragma unroll
    for (int p = 0; p < 2; ++p) {           // 512 16B segs per matrix
      int seg = p * 256 + t;
      int row = seg >> 2;
      int kb = (seg & 3) ^ (row & 3) ^ ((row >> 2) & 3);
      int goff = row * D + kOff + kb * 16;
      gload16(arow + goff, &ldsA[(p * 256 + w * 64) * 16]);
      gload16(brow + goff, &ldsB[(p * 256 + w * 64) * 16]);
    }
    __syncthreads();
    i32x8 aF[2];
    #pragma unroll
    for (int rb = 0; rb < 2; ++rb) {
      int rowA = waveRow * 64 + rb * 32 + lr;
      int sw = (rowA & 3) ^ ((rowA >> 2) & 3);
      i32x4 lo = *(const i32x4*)&ldsA[rowA * 64 + (cLo ^ sw) * 16];
      i32x4 hi = *(const i32x4*)&ldsA[rowA * 64 + (cHi ^ sw) * 16];
      aF[rb] = (i32x8){lo.x, lo.y, lo.z, lo.w, hi.x, hi.y, hi.z, hi.w};
    }
    #pragma unroll
    for (int cb = 0; cb < 2; ++cb) {
      int rowB = waveCol * 64 + cb * 32 + lr;
      int sw = (rowB & 3) ^ ((rowB >> 2) & 3);
      i32x4 lo = *(const i32x4*)&ldsB[rowB * 64 + (cLo ^ sw) * 16];
      i32x4 hi = *(const i32x4*)&ldsB[rowB * 64 + (cHi ^ sw) * 16];
      i32x8 bF = (i32x8){lo.x, lo.y, lo.z, lo.w, hi.x, hi.y, hi.z, hi.w};
      #pragma unroll
      for (int rb = 0; rb < 2; ++rb)
        acc[rb][cb] = __builtin_amdgcn_mfma_scale_f32_32x32x64_f8f6f4(
            aF[rb], bF, acc[rb][cb], 0, 0, 0, 127, 0, 127);
    }
  }

  // Packed epilogue: tt = 2A4*dot - A4*sqi - A4*sqj ; e = exp2(tt)
  // sum5 = e+e^2+e^4+e^8+e^16 (exp-squaring; bw_k = bw*2^k exactly)
  // C/D layout (shape-determined, dtype-independent): col=lane&31,
  // row=(r&3)+8*(r>>2)+4*(lane>>5)
  float c2A4 = 2.f * A4, nA4 = -A4;
  f32x2 lsum2 = {0.f, 0.f};
  bool diag = (bi == bj);
  #pragma unroll
  for (int cb = 0; cb < 2; ++cb) {
    int jj = waveCol * 64 + cb * 32 + lr;
    float bjv = nA4 * sqB[jj];
    #pragma unroll
    for (int rb = 0; rb < 2; ++rb) {
      #pragma unroll
      for (int r = 0; r < 16; r += 2) {
        int ii = waveRow * 64 + rb * 32 + (r & 3) + 8 * (r >> 2) + 4 * half;
        f32x2 dot2 = {acc[rb][cb][r], acc[rb][cb][r + 1]};
        f32x2 sq2 = {sqA[ii], sqA[ii + 1]};
        f32x2 tt = c2A4 * dot2 + (nA4 * sq2 + bjv);
        f32x2 e;
        e.x = __builtin_amdgcn_exp2f(tt.x);
        e.y = __builtin_amdgcn_exp2f(tt.y);
        f32x2 e2 = e * e, e4 = e2 * e2, e8 = e4 * e4, e16 = e8 * e8;
        f32x2 kern = ((e + e2) + (e4 + e8)) + e16;
        if (diag) {                          // block-uniform branch
          if (ii == jj) kern.x = 0.f;
          if (ii + 1 == jj) kern.y = 0.f;
        }
        lsum2 += kern;
      }
    }
  }
  float lsum = lsum2.x + lsum2.y;
  for (int o = 32; o > 0; o >>= 1) lsum += __shfl_down(lsum, o, 64);
  if (l == 0) redw[w] = lsum;
  __syncthreads();
  if (t == 0) {
    float tot = (redw[0] + redw[1]) + (redw[2] + redw[3]);
    float wgt = diag ? 1.f : 2.f;                               // symmetry weight
    float sgn = ((bi < HALF_B) == (bj < HALF_B)) ? 1.f : -1.f;  // s_i * s_j
    bpart[b] = tot * wgt * sgn;
  }
}

// ---- K4: final fp64 reduction + analytic diagonal + mean ----
__global__ void k_final(const float* __restrict__ bpart, float* __restrict__ out) {
  __shared__ double red[256];
  int t = threadIdx.x;
  double s = 0.0;
  for (int k = 0; k < 9; ++k) {
    int idx = k * 256 + t;
    if (idx < NTRI) s += (double)bpart[idx];
  }
  red[t] = s;
  __syncthreads();
  for (int st = 128; st > 0; st >>= 1) {
    if (t < st) red[t] += red[t + st];
    __syncthreads();
  }
  if (t == 0) {
    double total = red[0] + 5.0 * (double)N_TOT;  // diagonal: K_ii = 5, sign +1
    out[0] = (float)(total / ((double)NS * (double)NS));
  }
}

extern "C" void kernel_launch(void* const* d_in, const int* in_sizes, int n_in,
                              void* d_out, int out_size, void* d_ws, size_t ws_size,
                              hipStream_t stream) {
  const float* src = (const float*)d_in[0];
  const float* tgt = (const float*)d_in[1];
  float* out = (float*)d_out;
  char* ws = (char*)d_ws;
  unsigned char* Xb = (unsigned char*)ws;                       // 2 MB fp8 row-major
  float* sqv  = (float*)(ws + (4u << 20));                      // 32 KB row sq-norms
  float* pm   = (float*)(ws + (4u << 20) + (32u << 10));        // 256 KB col partials
  float* wsqp = (float*)(ws + (4u << 20) + (288u << 10));       // 1 KB sq partials
  float* coef = (float*)(ws + (4u << 20) + (289u << 10));       // 4 B
  float* bpart = (float*)(ws + (4u << 20) + (290u << 10));      // 8.3 KB tile partials

  hipLaunchKernelGGL(k_prep, dim3(256), dim3(256), 0, stream, src, tgt, Xb, sqv, pm, wsqp);
  hipLaunchKernelGGL(k_bw, dim3(1), dim3(256), 0, stream, pm, wsqp, coef);
  hipLaunchKernelGGL(k_main, dim3(NTRI), dim3(256), 0, stream, Xb, sqv, coef, bpart);
  hipLaunchKernelGGL(k_final, dim3(1), dim3(256), 0, stream, bpart, out);
}